// Round 4
// baseline (4102.297 us; speedup 1.0000x reference)
//
#include <hip/hip_runtime.h>

#define BB 32
#define TT 2048
#define DD 256
#define HH 512
#define NSL 8     // column slices per batch (one WG each)
#define SLW 64    // slice width (columns per WG)
#define KPT 64    // k-chunk per wave (8 waves x 64 lanes = 512 threads)

__device__ __forceinline__ float tanh_f(float x) {
    float e = __expf(2.f * x);
    return 1.f - 2.f / (e + 1.f);
}

// --- exchange primitives -----------------------------------------------------
// L2 path: sc0 = bypass L1, served by the XCD's shared L2. Writer's plain
// store is write-through L1 -> L2; reader's sc0 load sees it (same XCD).
__device__ __forceinline__ unsigned long long poll_l2(const unsigned long long* p) {
    unsigned long long v;
    asm volatile("global_load_dwordx2 %0, %1, off sc0\n\t"
                 "s_waitcnt vmcnt(0)"
                 : "=v"(v) : "v"(p) : "memory");
    return v;
}
__device__ __forceinline__ void store_l2(unsigned long long* p, unsigned long long v) {
    asm volatile("global_store_dwordx2 %0, %1, off sc0" :: "v"(p), "v"(v) : "memory");
}
// MALL path (always coherent, higher latency): relaxed agent-scope atomics.
__device__ __forceinline__ unsigned long long mall_load(const unsigned long long* p) {
    return __hip_atomic_load(p, __ATOMIC_RELAXED, __HIP_MEMORY_SCOPE_AGENT);
}
__device__ __forceinline__ void mall_store(unsigned long long* p, unsigned long long v) {
    __hip_atomic_store(p, v, __ATOMIC_RELAXED, __HIP_MEMORY_SCOPE_AGENT);
}

// ---------------------------------------------------------------------------
// Kernel A: xw[t][b][n] = bh[n] + sum_d X[b][t][d] * Wxh[d][n]
// Written IN PLACE into the d_out Y region (same [T][B][H] layout).
// ---------------------------------------------------------------------------
__global__ __launch_bounds__(256) void xw_gemm(const float* __restrict__ X,
                                               const float* __restrict__ Wxh,
                                               const float* __restrict__ bh,
                                               float* __restrict__ out) {
    __shared__ float As[16][68];
    __shared__ float Bs[16][68];
    const int tid = threadIdx.x;
    const int r0 = blockIdx.x * 64;
    const int n0 = blockIdx.y * 64;
    const int ty = tid >> 4, tx = tid & 15;

    float acc[4][4];
#pragma unroll
    for (int i = 0; i < 4; i++)
#pragma unroll
        for (int j = 0; j < 4; j++) acc[i][j] = 0.f;

    const int arow = tid >> 2;
    const int akq  = (tid & 3) * 4;
    const int brow = tid >> 4;
    const int bq   = (tid & 15) * 4;

    for (int k0 = 0; k0 < DD; k0 += 16) {
        float4 a4 = *reinterpret_cast<const float4*>(
            &X[(size_t)(r0 + arow) * DD + k0 + akq]);
        As[akq + 0][arow] = a4.x;
        As[akq + 1][arow] = a4.y;
        As[akq + 2][arow] = a4.z;
        As[akq + 3][arow] = a4.w;
        float4 b4 = *reinterpret_cast<const float4*>(
            &Wxh[(size_t)(k0 + brow) * HH + n0 + bq]);
        *reinterpret_cast<float4*>(&Bs[brow][bq]) = b4;
        __syncthreads();
#pragma unroll
        for (int kk = 0; kk < 16; kk++) {
            float a0 = As[kk][ty * 4 + 0];
            float a1 = As[kk][ty * 4 + 1];
            float a2 = As[kk][ty * 4 + 2];
            float a3 = As[kk][ty * 4 + 3];
            float4 bv = *reinterpret_cast<const float4*>(&Bs[kk][tx * 4]);
            acc[0][0] += a0 * bv.x; acc[0][1] += a0 * bv.y; acc[0][2] += a0 * bv.z; acc[0][3] += a0 * bv.w;
            acc[1][0] += a1 * bv.x; acc[1][1] += a1 * bv.y; acc[1][2] += a1 * bv.z; acc[1][3] += a1 * bv.w;
            acc[2][0] += a2 * bv.x; acc[2][1] += a2 * bv.y; acc[2][2] += a2 * bv.z; acc[2][3] += a2 * bv.w;
            acc[3][0] += a3 * bv.x; acc[3][1] += a3 * bv.y; acc[3][2] += a3 * bv.z; acc[3][3] += a3 * bv.w;
        }
        __syncthreads();
    }
    float4 bias = *reinterpret_cast<const float4*>(&bh[n0 + tx * 4]);
#pragma unroll
    for (int i = 0; i < 4; i++) {
        int r = r0 + ty * 4 + i;
        int b = r >> 11;
        int t = r & (TT - 1);
        float4 o;
        o.x = acc[i][0] + bias.x;
        o.y = acc[i][1] + bias.y;
        o.z = acc[i][2] + bias.z;
        o.w = acc[i][3] + bias.w;
        *reinterpret_cast<float4*>(
            &out[((size_t)t * BB + b) * HH + n0 + tx * 4]) = o;
    }
}

// ---------------------------------------------------------------------------
// Kernel B: distributed scan, same-XCD L2 exchange with MALL fallback.
// 256 WGs = 32 batches x 8 column slices, 1 WG/CU; peers of batch b all have
// bid%8 == b%8 -> same XCD under round-robin dispatch (perf heuristic only;
// correctness guaranteed by the per-slot MALL fallback).
//
// Per step (ONE barrier):
//   matvec own k-chunk (h slice in own wave's LDS window)
//   -> part[t&1][kq][lane] -> __syncthreads
//   -> wave 0: reduce 8 parts + xw, tanh, publish {val,tag=t+1} (L2 + MALL),
//      store Y, prefetch next xw
//   -> every wave polls ITS slice's 64 slots (wave kq <-> slice kq ==
//      exactly the h values its next matvec needs), fills its LDS window,
//      lgkmcnt, proceeds -- no post-poll barrier.
// WAR on part[] broken by the t&1 double buffer; the publish-follows-read
// ordering closes the cross-WG chain at gap 2 (slot reuse only at t+2).
// Tags 1..2048 never match the 0xAA poison; kernel-boundary L2 flush
// (already load-bearing for xw_gemm -> scan) prevents cross-launch staleness.
// ---------------------------------------------------------------------------
__global__ __launch_bounds__(512) void scan_kernel(const float* __restrict__ Whh,
                                                   float* __restrict__ Y,
                                                   unsigned long long* __restrict__ ex) {
    __shared__ float h_lds[HH];
    __shared__ float part[2][NSL][SLW];
    const int tid = threadIdx.x;
    const int bid = blockIdx.x;
    const int s = bid >> 5;       // slice 0..7
    const int b = bid & 31;       // batch 0..31
    const int n0 = s * SLW;
    const int lane = tid & 63;
    const int kq = tid >> 6;      // wave id == consumed slice id
    const int k0 = kq * KPT;

    // one-time: Whh slice into registers, w[j] = Whh[k0+j][n0+lane]
    float w[KPT];
#pragma unroll
    for (int j = 0; j < KPT; j++)
        w[j] = Whh[(size_t)(k0 + j) * HH + n0 + lane];

    h_lds[tid] = 0.f;
    __syncthreads();

    const bool red = (kq == 0);   // wave 0 reduces + publishes column `lane`
    float xw_cur = 0.f;
    if (red) xw_cur = Y[(size_t)b * HH + n0 + lane];

    bool use_mall = false;

    for (int t = 0; t < TT; t++) {
        const int p = t & 1;
        // matvec over own k-chunk (broadcast LDS reads, weights in VGPRs)
        float a0 = 0.f, a1 = 0.f, a2 = 0.f, a3 = 0.f;
#pragma unroll
        for (int j = 0; j < KPT; j += 4) {
            float4 h4 = *reinterpret_cast<const float4*>(&h_lds[k0 + j]);
            a0 += h4.x * w[j + 0];
            a1 += h4.y * w[j + 1];
            a2 += h4.z * w[j + 2];
            a3 += h4.w * w[j + 3];
        }
        part[p][kq][lane] = (a0 + a1) + (a2 + a3);
        __syncthreads();   // the only barrier per step

        if (red) {
            float ssum = part[p][0][lane] + part[p][1][lane] +
                         part[p][2][lane] + part[p][3][lane] +
                         part[p][4][lane] + part[p][5][lane] +
                         part[p][6][lane] + part[p][7][lane] + xw_cur;
            float hn = tanh_f(ssum);
            unsigned long long pk =
                ((unsigned long long)(unsigned)(t + 1) << 32) |
                (unsigned long long)__float_as_uint(hn);
            unsigned long long* q = &ex[(((size_t)p * BB + b) << 9) + n0 + lane];
            store_l2(q, pk);          // fast path: shared XCD L2
            mall_store(q, pk);        // fallback copy: always coherent
            Y[((size_t)t * BB + b) * HH + n0 + lane] = hn;
            if (t + 1 < TT)
                xw_cur = Y[((size_t)(t + 1) * BB + b) * HH + n0 + lane];
        }

        if (t + 1 < TT) {
            // wave kq polls slice kq, slot = kq*64+lane == tid
            unsigned long long* q = &ex[(((size_t)p * BB + b) << 9) + tid];
            const unsigned want = (unsigned)(t + 1);
            unsigned long long v = 0;
            if (!use_mall) {
                int spins = 0;
                for (;;) {
                    v = poll_l2(q);
                    if ((unsigned)(v >> 32) == want) break;
                    if (++spins > 1500) { use_mall = true; break; }
                }
            }
            if (use_mall) {
                do {
                    v = mall_load(q);
                } while ((unsigned)(v >> 32) != want);
            }
            h_lds[tid] = __uint_as_float((unsigned)v);
            asm volatile("s_waitcnt lgkmcnt(0)" ::: "memory");
            // no barrier: h window is wave-private, part[] is double-buffered
        }
    }
}

// ---------------------------------------------------------------------------
// Kernel C: attention, one WG per batch.
//   scores[b,t] = tanh(Y[t,b,:] . v[b]),  v[b] = KW @ (QW^T Y[T-1,b])
// ---------------------------------------------------------------------------
__global__ __launch_bounds__(512) void attn_kernel(const float* __restrict__ QW,
                                                   const float* __restrict__ KW,
                                                   const float* __restrict__ Y,
                                                   float* __restrict__ c) {
    __shared__ float yl[HH];
    __shared__ float q0[DD];
    __shared__ float vv[HH];
    __shared__ float sc[TT];
    __shared__ float red[16];
    const int tid = threadIdx.x;
    const int b = blockIdx.x;
    const int w = tid >> 6;
    const int l = tid & 63;

    if (tid < HH) yl[tid] = Y[((size_t)(TT - 1) * BB + b) * HH + tid];
    __syncthreads();

    if (tid < DD) {
        float s = 0.f;
#pragma unroll 8
        for (int h = 0; h < HH; h++) s += yl[h] * QW[(size_t)h * DD + tid];
        q0[tid] = s;
    }
    __syncthreads();

    {
        float s = 0.f;
        const int nn = tid;
#pragma unroll 4
        for (int d = 0; d < DD; d += 4) {
            float4 kw = *reinterpret_cast<const float4*>(&KW[(size_t)nn * DD + d]);
            float4 q4 = *reinterpret_cast<const float4*>(&q0[d]);
            s += kw.x * q4.x + kw.y * q4.y + kw.z * q4.z + kw.w * q4.w;
        }
        vv[nn] = s;
    }
    __syncthreads();

    for (int i = 0; i < TT / 8; i++) {
        int t = i * 8 + w;
        const float* yr = &Y[((size_t)t * BB + b) * HH + l * 8];
        float4 y0 = *reinterpret_cast<const float4*>(yr);
        float4 y1 = *reinterpret_cast<const float4*>(yr + 4);
        float4 v0 = *reinterpret_cast<const float4*>(&vv[l * 8]);
        float4 v1 = *reinterpret_cast<const float4*>(&vv[l * 8 + 4]);
        float s = y0.x * v0.x + y0.y * v0.y + y0.z * v0.z + y0.w * v0.w +
                  y1.x * v1.x + y1.y * v1.y + y1.z * v1.z + y1.w * v1.w;
#pragma unroll
        for (int off = 32; off > 0; off >>= 1) s += __shfl_xor(s, off);
        if (l == 0) sc[t] = tanh_f(s);
    }
    __syncthreads();

    float m = -1e30f;
    for (int i = tid; i < TT; i += 512) m = fmaxf(m, sc[i]);
#pragma unroll
    for (int off = 32; off > 0; off >>= 1) m = fmaxf(m, __shfl_xor(m, off));
    if (l == 0) red[w] = m;
    __syncthreads();
    float gm = red[0];
#pragma unroll
    for (int i = 1; i < 8; i++) gm = fmaxf(gm, red[i]);

    float ls = 0.f;
    for (int i = tid; i < TT; i += 512) {
        float e = __expf(sc[i] - gm);
        sc[i] = e;
        ls += e;
    }
#pragma unroll
    for (int off = 32; off > 0; off >>= 1) ls += __shfl_xor(ls, off);
    __syncthreads();
    if (l == 0) red[8 + w] = ls;
    __syncthreads();
    float tot = 0.f;
#pragma unroll
    for (int i = 0; i < 8; i++) tot += red[8 + i];
    float inv = 1.f / tot;
    for (int i = tid; i < TT; i += 512) sc[i] *= inv;
    __syncthreads();

    {
        const int nn = tid;
        float acc = 0.f;
        for (int t = 0; t < TT; t += 4) {
            float4 a4 = *reinterpret_cast<const float4*>(&sc[t]);
            acc += a4.x * Y[((size_t)(t + 0) * BB + b) * HH + nn];
            acc += a4.y * Y[((size_t)(t + 1) * BB + b) * HH + nn];
            acc += a4.z * Y[((size_t)(t + 2) * BB + b) * HH + nn];
            acc += a4.w * Y[((size_t)(t + 3) * BB + b) * HH + nn];
        }
        c[(size_t)b * HH + nn] = acc;
    }
}

// ---------------------------------------------------------------------------
extern "C" void kernel_launch(void* const* d_in, const int* in_sizes, int n_in,
                              void* d_out, int out_size, void* d_ws, size_t ws_size,
                              hipStream_t stream) {
    const float* X   = (const float*)d_in[0];
    const float* Wxh = (const float*)d_in[1];
    const float* Whh = (const float*)d_in[2];
    const float* bh  = (const float*)d_in[3];
    const float* QW  = (const float*)d_in[4];
    const float* KW  = (const float*)d_in[5];
    float* out  = (float*)d_out;
    float* Ybuf = out;                                   // [T][B][H]
    float* cbuf = out + (size_t)TT * BB * HH;            // [B][H]
    unsigned long long* ex = (unsigned long long*)d_ws;  // [2][BB][HH] 8B slots

    dim3 ga(BB * TT / 64, HH / 64);
    xw_gemm<<<ga, 256, 0, stream>>>(X, Wxh, bh, Ybuf);
    scan_kernel<<<BB * NSL, 512, 0, stream>>>(Whh, Ybuf, ex);
    attn_kernel<<<BB, 512, 0, stream>>>(QW, KW, Ybuf, cbuf);
}